// Round 1
// baseline (220.781 us; speedup 1.0000x reference)
//
#include <hip/hip_runtime.h>
#include <hip/hip_bf16.h>

// out[b,o] = sum_i x[b,i] * (W[h,i,o] + 0.1*dW[h*ns+s, i, o])
// IN=10, OUT=8 hardcoded (structure depends on them).
// 2 lanes per token: lane half=0 handles outputs 0..3, half=1 handles 4..7.
// All W/dW accesses are 16B-aligned float4; output store is coalesced float4.

__global__ __launch_bounds__(256) void frag_dist_kernel(
    const float* __restrict__ x,
    const float* __restrict__ W,
    const float* __restrict__ dW,
    const int* __restrict__ head_ix,
    const int* __restrict__ split_ix,
    const int* __restrict__ nsp,
    float* __restrict__ out,
    int B)
{
    const int gid = blockIdx.x * blockDim.x + threadIdx.x;
    const int t = gid >> 1;          // token index
    const int half = gid & 1;        // which half of the 8 outputs
    if (t >= B) return;

    const int ns = nsp[0];
    const int h = head_ix[t];
    const int g = h * ns + split_ix[t];

    const float* __restrict__ wrow = W + (size_t)h * 80 + (size_t)half * 4;
    const float* __restrict__ drow = dW + (size_t)g * 80 + (size_t)half * 4;

    // x row: 40 bytes, 8B-aligned -> 5x float2
    const float2* __restrict__ x2 = reinterpret_cast<const float2*>(x + (size_t)t * 10);
    float2 p0 = x2[0], p1 = x2[1], p2 = x2[2], p3 = x2[3], p4 = x2[4];
    float xv[10] = {p0.x, p0.y, p1.x, p1.y, p2.x, p2.y, p3.x, p3.y, p4.x, p4.y};

    float4 acc = make_float4(0.f, 0.f, 0.f, 0.f);
#pragma unroll
    for (int i = 0; i < 10; ++i) {
        const float4 w4 = *reinterpret_cast<const float4*>(wrow + i * 8);
        const float4 d4 = *reinterpret_cast<const float4*>(drow + i * 8);
        const float xi = xv[i];
        const float xs = 0.1f * xi;
        acc.x = fmaf(xi, w4.x, fmaf(xs, d4.x, acc.x));
        acc.y = fmaf(xi, w4.y, fmaf(xs, d4.y, acc.y));
        acc.z = fmaf(xi, w4.z, fmaf(xs, d4.z, acc.z));
        acc.w = fmaf(xi, w4.w, fmaf(xs, d4.w, acc.w));
    }

    *reinterpret_cast<float4*>(out + (size_t)t * 8 + (size_t)half * 4) = acc;
}

extern "C" void kernel_launch(void* const* d_in, const int* in_sizes, int n_in,
                              void* d_out, int out_size, void* d_ws, size_t ws_size,
                              hipStream_t stream) {
    const float* x        = (const float*)d_in[0];
    const float* W        = (const float*)d_in[1];
    const float* dW       = (const float*)d_in[2];
    const int*   head_ix  = (const int*)d_in[3];
    const int*   split_ix = (const int*)d_in[4];
    const int*   nsp      = (const int*)d_in[5];
    float* out = (float*)d_out;

    const int B = in_sizes[0] / 10;  // x is [B, 10]
    const long long total = 2LL * B; // 2 lanes per token
    const int block = 256;
    const int grid = (int)((total + block - 1) / block);

    frag_dist_kernel<<<grid, block, 0, stream>>>(x, W, dW, head_ix, split_ix, nsp, out, B);
}

// Round 2
// 220.573 us; speedup vs baseline: 1.0009x; 1.0009x over previous
//
#include <hip/hip_runtime.h>
#include <hip/hip_bf16.h>

// out[b,o] = sum_i x[b,i] * (W[h,i,o] + 0.1*dW[h*ns+s, i, o])
// IN=10, OUT=8 hardcoded. 2 lanes per token: half=0 -> outputs 0..3, half=1 -> 4..7.
// All table reads are 16B-aligned float4. Full prefetch into registers to
// maximize memory-level parallelism (latency-bound gather).

__global__ __launch_bounds__(256) void frag_dist_kernel(
    const float* __restrict__ x,
    const float* __restrict__ W,
    const float* __restrict__ dW,
    const int* __restrict__ head_ix,
    const int* __restrict__ split_ix,
    const int* __restrict__ nsp,
    float* __restrict__ out,
    int B)
{
    const int gid = blockIdx.x * blockDim.x + threadIdx.x;
    const int t = gid >> 1;          // token index
    const int half = gid & 1;        // which half of the 8 outputs
    if (t >= B) return;

    const int ns = nsp[0];
    const int h = head_ix[t];
    const int g = h * ns + split_ix[t];

    const float* __restrict__ wrow = W + (size_t)h * 80 + (size_t)half * 4;
    const float* __restrict__ drow = dW + (size_t)g * 80 + (size_t)half * 4;
    const float2* __restrict__ x2 = reinterpret_cast<const float2*>(x + (size_t)t * 10);

    // ---- issue ALL loads before any use: 5 float2 (x) + 20 float4 (tables) ----
    float2 p0 = x2[0], p1 = x2[1], p2 = x2[2], p3 = x2[3], p4 = x2[4];

    float4 w0 = *reinterpret_cast<const float4*>(wrow + 0 * 8);
    float4 w1 = *reinterpret_cast<const float4*>(wrow + 1 * 8);
    float4 w2 = *reinterpret_cast<const float4*>(wrow + 2 * 8);
    float4 w3 = *reinterpret_cast<const float4*>(wrow + 3 * 8);
    float4 w4 = *reinterpret_cast<const float4*>(wrow + 4 * 8);
    float4 w5 = *reinterpret_cast<const float4*>(wrow + 5 * 8);
    float4 w6 = *reinterpret_cast<const float4*>(wrow + 6 * 8);
    float4 w7 = *reinterpret_cast<const float4*>(wrow + 7 * 8);
    float4 w8 = *reinterpret_cast<const float4*>(wrow + 8 * 8);
    float4 w9 = *reinterpret_cast<const float4*>(wrow + 9 * 8);

    float4 d0 = *reinterpret_cast<const float4*>(drow + 0 * 8);
    float4 d1 = *reinterpret_cast<const float4*>(drow + 1 * 8);
    float4 d2 = *reinterpret_cast<const float4*>(drow + 2 * 8);
    float4 d3 = *reinterpret_cast<const float4*>(drow + 3 * 8);
    float4 d4 = *reinterpret_cast<const float4*>(drow + 4 * 8);
    float4 d5 = *reinterpret_cast<const float4*>(drow + 5 * 8);
    float4 d6 = *reinterpret_cast<const float4*>(drow + 6 * 8);
    float4 d7 = *reinterpret_cast<const float4*>(drow + 7 * 8);
    float4 d8 = *reinterpret_cast<const float4*>(drow + 8 * 8);
    float4 d9 = *reinterpret_cast<const float4*>(drow + 9 * 8);

    const float xv[10] = {p0.x, p0.y, p1.x, p1.y, p2.x, p2.y, p3.x, p3.y, p4.x, p4.y};

    float4 acc = make_float4(0.f, 0.f, 0.f, 0.f);
    const float4 wv[10] = {w0, w1, w2, w3, w4, w5, w6, w7, w8, w9};
    const float4 dv[10] = {d0, d1, d2, d3, d4, d5, d6, d7, d8, d9};
#pragma unroll
    for (int i = 0; i < 10; ++i) {
        const float xi = xv[i];
        const float xs = 0.1f * xi;
        acc.x = fmaf(xi, wv[i].x, fmaf(xs, dv[i].x, acc.x));
        acc.y = fmaf(xi, wv[i].y, fmaf(xs, dv[i].y, acc.y));
        acc.z = fmaf(xi, wv[i].z, fmaf(xs, dv[i].z, acc.z));
        acc.w = fmaf(xi, wv[i].w, fmaf(xs, dv[i].w, acc.w));
    }

    *reinterpret_cast<float4*>(out + (size_t)t * 8 + (size_t)half * 4) = acc;
}

extern "C" void kernel_launch(void* const* d_in, const int* in_sizes, int n_in,
                              void* d_out, int out_size, void* d_ws, size_t ws_size,
                              hipStream_t stream) {
    const float* x        = (const float*)d_in[0];
    const float* W        = (const float*)d_in[1];
    const float* dW       = (const float*)d_in[2];
    const int*   head_ix  = (const int*)d_in[3];
    const int*   split_ix = (const int*)d_in[4];
    const int*   nsp      = (const int*)d_in[5];
    float* out = (float*)d_out;

    const int B = in_sizes[0] / 10;  // x is [B, 10]
    const long long total = 2LL * B; // 2 lanes per token
    const int block = 256;
    const int grid = (int)((total + block - 1) / block);

    frag_dist_kernel<<<grid, block, 0, stream>>>(x, W, dW, head_ix, split_ix, nsp, out, B);
}